// Round 10
// baseline (376.157 us; speedup 1.0000x reference)
//
#include <hip/hip_runtime.h>

#define T_IN   512
#define T_OUT  128
#define BATCH  65536

typedef float v2f __attribute__((ext_vector_type(2)));

__device__ __forceinline__ float rcp_fast(float v) { return __builtin_amdgcn_rcpf(v); }
__device__ __forceinline__ float exp2_fast(float v) { return __builtin_amdgcn_exp2f(v); }

// ---- VOP3P packed fp32 ops, forced via asm (all variants proven in R7) ----
__device__ __forceinline__ v2f pk_fma(v2f a, v2f b, v2f c) {
    v2f d;
    asm("v_pk_fma_f32 %0, %1, %2, %3" : "=v"(d) : "v"(a), "v"(b), "v"(c));
    return d;
}
__device__ __forceinline__ v2f pk_mul(v2f a, v2f b) {
    v2f d;
    asm("v_pk_mul_f32 %0, %1, %2" : "=v"(d) : "v"(a), "v"(b));
    return d;
}
// acc += w * {h.lo, h.lo}   (src1 broadcast-lo via op_sel)
__device__ __forceinline__ void pk_fma_L(v2f& acc, v2f w, v2f h) {
    asm("v_pk_fma_f32 %0, %1, %2, %0 op_sel:[0,0,0] op_sel_hi:[1,0,1]"
        : "+v"(acc) : "v"(w), "v"(h));
}
// acc += w * {h.hi, h.hi}   (src1 broadcast-hi via op_sel)
__device__ __forceinline__ void pk_fma_H(v2f& acc, v2f w, v2f h) {
    asm("v_pk_fma_f32 %0, %1, %2, %0 op_sel:[0,1,0] op_sel_hi:[1,1,1]"
        : "+v"(acc) : "v"(w), "v"(h));
}
// out-of-place seeded variant (c = bias), src1 broadcast-lo
__device__ __forceinline__ v2f pk_fma_L0(v2f w, v2f h, v2f c) {
    v2f d;
    asm("v_pk_fma_f32 %0, %1, %2, %3 op_sel:[0,0,0] op_sel_hi:[1,0,1]"
        : "=v"(d) : "v"(w), "v"(h), "v"(c));
    return d;
}

// DPP cross-lane mov (quad_perm, intra-quad).
template<int CTRL>
__device__ __forceinline__ float dppf(float v) {
    return __int_as_float(__builtin_amdgcn_mov_dpp(__float_as_int(v), CTRL, 0xF, 0xF, false));
}
#define QP_XOR1 0xB1   // quad_perm [1,0,3,2] : lane ^= 1
#define QP_XOR2 0x4E   // quad_perm [2,3,0,1] : lane ^= 2
#define QP_XOR3 0x1B   // quad_perm [3,2,1,0] : lane ^= 3

// R7 structure (4 lanes/elem, pair-packed units, 6-DPP allgather, exp2+merged
// rcp activations, scalar reciprocal distribution) with TWO independent batch
// elements per thread (slots A/B) to fill the serial-chain issue bubbles seen
// at VALUBusy=81%. Cell body is R7-verbatim, parameterized by the state array.
__global__ __launch_bounds__(256, 2) void gru_seq2seq(
    const float* __restrict__ x,
    const float* __restrict__ eWih, const float* __restrict__ eWhh,
    const float* __restrict__ eBih, const float* __restrict__ eBhh,
    const float* __restrict__ dWih, const float* __restrict__ dWhh,
    const float* __restrict__ dBih, const float* __restrict__ dBhh,
    const float* __restrict__ fcW,  const float* __restrict__ fcB,
    float* __restrict__ out)
{
    const int tid = threadIdx.x;
    const int u   = tid & 3;                        // owns units 2u, 2u+1
    const int e0  = (int)blockIdx.x * 128 + (tid >> 2);  // slot A; slot B = e0+64

    const float CR = -1.44269504088896340736f;      // -log2(e)
    const float CN =  2.88539008177792681472f;      //  2*log2(e)

    const int r0 = 2*u, r1 = 2*u + 1;               // owned gate rows (per gate)

    // weights: index [2m+lh] multiplies h_{2(u^m)+lh} (XOR-of-pair order); shared by slots
    v2f wr[8], wz[8], wn[8];
    v2f wirp, wizp, winp;                           // W_ih row pairs
    v2f brp, bzp, bnp, binp;                        // bias pairs

    auto load_w = [&](const float* Wih, const float* Whh,
                      const float* Bih, const float* Bhh) {
        #pragma unroll
        for (int m = 0; m < 4; ++m) {
            #pragma unroll
            for (int lh = 0; lh < 2; ++lh) {
                const int j = 2*(u^m) + lh;
                wr[2*m+lh] = v2f{ Whh[r0*8      + j] * CR, Whh[r1*8      + j] * CR };
                wz[2*m+lh] = v2f{ Whh[(r0+8)*8  + j] * CR, Whh[(r1+8)*8  + j] * CR };
                wn[2*m+lh] = v2f{ Whh[(r0+16)*8 + j] * CN, Whh[(r1+16)*8 + j] * CN };
            }
        }
        wirp = v2f{ Wih[r0]    * CR, Wih[r1]    * CR };
        wizp = v2f{ Wih[r0+8]  * CR, Wih[r1+8]  * CR };
        winp = v2f{ Wih[r0+16] * CN, Wih[r1+16] * CN };
        brp  = v2f{ (Bih[r0]   + Bhh[r0])   * CR, (Bih[r1]   + Bhh[r1])   * CR };
        bzp  = v2f{ (Bih[r0+8] + Bhh[r0+8]) * CR, (Bih[r1+8] + Bhh[r1+8]) * CR };
        bnp  = v2f{ Bhh[r0+16] * CN,              Bhh[r1+16] * CN };
        binp = v2f{ Bih[r0+16] * CN,              Bih[r1+16] * CN };
    };

    load_w(eWih, eWhh, eBih, eBhh);

    const v2f C_NEG2 = {-2.f, -2.f};
    const v2f C_ONE  = { 1.f,  1.f};
    const v2f C_M1   = {-1.f, -1.f};

    v2f hpA[4], hpB[4];                             // per-slot state
    #pragma unroll
    for (int m = 0; m < 4; ++m) { hpA[m] = v2f{0.f, 0.f}; hpB[m] = v2f{0.f, 0.f}; }

    // R7-verbatim cell, operating on the given slot state.
    auto cell = [&](v2f (&hp)[4], float xs) {
        const v2f xv = { xs, xs };
        v2f ar = pk_fma_L0(wr[0], hp[0], brp);
        v2f az = pk_fma_L0(wz[0], hp[0], bzp);
        v2f an = pk_fma_L0(wn[0], hp[0], bnp);
        pk_fma_H(ar, wr[1], hp[0]);
        pk_fma_H(az, wz[1], hp[0]);
        pk_fma_H(an, wn[1], hp[0]);
        #pragma unroll
        for (int m = 1; m < 4; ++m) {
            pk_fma_L(ar, wr[2*m],   hp[m]);
            pk_fma_L(az, wz[2*m],   hp[m]);
            pk_fma_L(an, wn[2*m],   hp[m]);
            pk_fma_H(ar, wr[2*m+1], hp[m]);
            pk_fma_H(az, wz[2*m+1], hp[m]);
            pk_fma_H(an, wn[2*m+1], hp[m]);
        }
        const v2f sr = pk_fma(xv, wirp, ar);        // scaled pre-act r (rows 2u,2u+1)
        const v2f sz = pk_fma(xv, wizp, az);        // scaled pre-act z

        // 4 sigmoids, ONE rcp (scalar glue, proven in R7)
        const float er0 = exp2_fast(sr.x), er1 = exp2_fast(sr.y);
        const float ez0 = exp2_fast(sz.x), ez1 = exp2_fast(sz.y);
        const float dr0 = 1.0f + er0, dr1 = 1.0f + er1;
        const float dz0 = 1.0f + ez0, dz1 = 1.0f + ez1;
        const float P0  = dr0 * dz0,  P1  = dr1 * dz1;
        const float rp  = rcp_fast(P0 * P1);
        const float rpA = rp * P1,    rpB = rp * P0;    // 1/P0, 1/P1
        const v2f r01 = { dz0 * rpA, dz1 * rpB };
        const v2f z01 = { dr0 * rpA, dr1 * rpB };

        // n = tanh-form with shared rcp across the pair
        v2f pre = pk_fma(xv, winp, binp);
        pre = pk_fma(r01, an, pre);
        const float en0 = exp2_fast(pre.x), en1 = exp2_fast(pre.y);
        const float Dn0 = 1.0f + en0, Dn1 = 1.0f + en1;
        const float rpn = rcp_fast(Dn0 * Dn1);
        const v2f rn  = { rpn * Dn1, rpn * Dn0 };
        const v2f n01 = pk_fma(C_NEG2, rn, C_ONE);  // tanh

        const v2f hm = pk_fma(n01, C_M1, hp[0]);    // h - n
        hp[0] = pk_fma(z01, hm, n01);               // h' = n + z*(h-n)

        // allgather: 6 DPP movs (intra-quad)
        const float g0 = hp[0].x, g1 = hp[0].y;
        hp[1] = v2f{ dppf<QP_XOR1>(g0), dppf<QP_XOR1>(g1) };
        hp[2] = v2f{ dppf<QP_XOR2>(g0), dppf<QP_XOR2>(g1) };
        hp[3] = v2f{ dppf<QP_XOR3>(g0), dppf<QP_XOR3>(g1) };
    };

    // -------- encoder: 512 steps, dual-stream prefetch depth 2 (R5 pattern) --------
    const float* xp = x + e0;
    float xa0 = xp[0],     xb0 = xp[64];
    float xa1 = xp[BATCH], xb1 = xp[BATCH + 64];
    xp += 2 * (size_t)BATCH;
    #pragma unroll 2
    for (int t = 0; t < T_IN - 2; ++t) {
        const float xa2 = xp[0];
        const float xb2 = xp[64];
        xp += BATCH;
        cell(hpA, xa0);
        cell(hpB, xb0);
        xa0 = xa1; xa1 = xa2;
        xb0 = xb1; xb1 = xb2;
    }
    cell(hpA, xa0); cell(hpB, xb0);     // t = 510
    cell(hpA, xa1); cell(hpB, xb1);     // t = 511; xa1/xb1 == x[511]

    // ---------------- decoder: 128 steps ----------------
    load_w(dWih, dWhh, dBih, dBhh);
    const v2f fwp = v2f{ fcW[r0], fcW[r1] };
    const float fb = fcB[0];

    float inpA = xa1, inpB = xb1;
    float* outp = out + e0;
    #pragma unroll 1
    for (int t = 0; t < T_OUT; ++t) {
        cell(hpA, inpA);
        cell(hpB, inpB);
        // y = fc(h'): pair-product then quad butterfly reduce (per slot)
        const v2f ayA = pk_mul(fwp, hpA[0]);
        const v2f ayB = pk_mul(fwp, hpB[0]);
        float sA = ayA.x + ayA.y;
        float sB = ayB.x + ayB.y;
        sA += dppf<QP_XOR1>(sA);
        sB += dppf<QP_XOR1>(sB);
        sA += dppf<QP_XOR2>(sA);
        sB += dppf<QP_XOR2>(sB);
        const float yA = sA + fb;
        const float yB = sB + fb;
        if (u == 0) {
            outp[t * BATCH]      = yA;
            outp[t * BATCH + 64] = yB;
        }
        inpA = yA;
        inpB = yB;
    }
}

extern "C" void kernel_launch(void* const* d_in, const int* in_sizes, int n_in,
                              void* d_out, int out_size, void* d_ws, size_t ws_size,
                              hipStream_t stream) {
    const float* x    = (const float*)d_in[0];
    const float* eWih = (const float*)d_in[1];
    const float* eWhh = (const float*)d_in[2];
    const float* eBih = (const float*)d_in[3];
    const float* eBhh = (const float*)d_in[4];
    const float* dWih = (const float*)d_in[5];
    const float* dWhh = (const float*)d_in[6];
    const float* dBih = (const float*)d_in[7];
    const float* dBhh = (const float*)d_in[8];
    const float* fcW  = (const float*)d_in[9];
    const float* fcB  = (const float*)d_in[10];
    float* out = (float*)d_out;

    dim3 grid(BATCH / 128);  // 512 blocks; 4 lanes/elem, 2 elems/thread
    dim3 block(256);
    gru_seq2seq<<<grid, block, 0, stream>>>(x, eWih, eWhh, eBih, eBhh,
                                            dWih, dWhh, dBih, dBhh,
                                            fcW, fcB, out);
}

// Round 11
// 348.470 us; speedup vs baseline: 1.0795x; 1.0795x over previous
//
#include <hip/hip_runtime.h>

#define T_IN   512
#define T_OUT  128
#define BATCH  65536

typedef float v2f __attribute__((ext_vector_type(2)));

__device__ __forceinline__ float rcp_fast(float v) { return __builtin_amdgcn_rcpf(v); }
__device__ __forceinline__ float exp2_fast(float v) { return __builtin_amdgcn_exp2f(v); }

// ---- VOP3P packed fp32 ops, forced via asm (all variants proven in R7) ----
__device__ __forceinline__ v2f pk_fma(v2f a, v2f b, v2f c) {
    v2f d;
    asm("v_pk_fma_f32 %0, %1, %2, %3" : "=v"(d) : "v"(a), "v"(b), "v"(c));
    return d;
}
__device__ __forceinline__ v2f pk_mul(v2f a, v2f b) {
    v2f d;
    asm("v_pk_mul_f32 %0, %1, %2" : "=v"(d) : "v"(a), "v"(b));
    return d;
}
// acc += w * {h.lo, h.lo}   (src1 broadcast-lo via op_sel)
__device__ __forceinline__ void pk_fma_L(v2f& acc, v2f w, v2f h) {
    asm("v_pk_fma_f32 %0, %1, %2, %0 op_sel:[0,0,0] op_sel_hi:[1,0,1]"
        : "+v"(acc) : "v"(w), "v"(h));
}
// acc += w * {h.hi, h.hi}   (src1 broadcast-hi via op_sel)
__device__ __forceinline__ void pk_fma_H(v2f& acc, v2f w, v2f h) {
    asm("v_pk_fma_f32 %0, %1, %2, %0 op_sel:[0,1,0] op_sel_hi:[1,1,1]"
        : "+v"(acc) : "v"(w), "v"(h));
}
// out-of-place seeded variant (c = bias), src1 broadcast-lo
__device__ __forceinline__ v2f pk_fma_L0(v2f w, v2f h, v2f c) {
    v2f d;
    asm("v_pk_fma_f32 %0, %1, %2, %3 op_sel:[0,0,0] op_sel_hi:[1,0,1]"
        : "=v"(d) : "v"(w), "v"(h), "v"(c));
    return d;
}

// DPP cross-lane mov (quad_perm, intra-quad).
template<int CTRL>
__device__ __forceinline__ float dppf(float v) {
    return __int_as_float(__builtin_amdgcn_mov_dpp(__float_as_int(v), CTRL, 0xF, 0xF, false));
}
#define QP_XOR1 0xB1   // quad_perm [1,0,3,2] : lane ^= 1
#define QP_XOR2 0x4E   // quad_perm [2,3,0,1] : lane ^= 2
#define QP_XOR3 0x1B   // quad_perm [3,2,1,0] : lane ^= 3

// R7 structure verbatim (4 lanes/elem, pair-packed units, op_sel-broadcast
// matmul, exp2 + merged-rcp activations, 6-DPP allgather) + a one-time
// WAVE-SLOT STAGGER: co-resident waves run identical code and convoy (all in
// the serial trans chain simultaneously -> 19% issue idle). Skewing program
// position by hw wave-slot desynchronizes the convoy so one wave's matmul
// burst fills another's activation-chain stall.
__global__ __launch_bounds__(256, 4) void gru_seq2seq(
    const float* __restrict__ x,
    const float* __restrict__ eWih, const float* __restrict__ eWhh,
    const float* __restrict__ eBih, const float* __restrict__ eBhh,
    const float* __restrict__ dWih, const float* __restrict__ dWhh,
    const float* __restrict__ dBih, const float* __restrict__ dBhh,
    const float* __restrict__ fcW,  const float* __restrict__ fcB,
    float* __restrict__ out)
{
    const int tid = threadIdx.x;
    const int u   = tid & 3;                        // owns units 2u, 2u+1
    const int e0  = (int)blockIdx.x * 64 + (tid >> 2);

    const float CR = -1.44269504088896340736f;      // -log2(e)
    const float CN =  2.88539008177792681472f;      //  2*log2(e)

    const int r0 = 2*u, r1 = 2*u + 1;               // owned gate rows (per gate)

    // weights: index [2m+lh] multiplies h_{2(u^m)+lh} (XOR-of-pair order)
    v2f wr[8], wz[8], wn[8];
    v2f wirp, wizp, winp;                           // W_ih row pairs
    v2f brp, bzp, bnp, binp;                        // bias pairs

    auto load_w = [&](const float* Wih, const float* Whh,
                      const float* Bih, const float* Bhh) {
        #pragma unroll
        for (int m = 0; m < 4; ++m) {
            #pragma unroll
            for (int lh = 0; lh < 2; ++lh) {
                const int j = 2*(u^m) + lh;
                wr[2*m+lh] = v2f{ Whh[r0*8      + j] * CR, Whh[r1*8      + j] * CR };
                wz[2*m+lh] = v2f{ Whh[(r0+8)*8  + j] * CR, Whh[(r1+8)*8  + j] * CR };
                wn[2*m+lh] = v2f{ Whh[(r0+16)*8 + j] * CN, Whh[(r1+16)*8 + j] * CN };
            }
        }
        wirp = v2f{ Wih[r0]    * CR, Wih[r1]    * CR };
        wizp = v2f{ Wih[r0+8]  * CR, Wih[r1+8]  * CR };
        winp = v2f{ Wih[r0+16] * CN, Wih[r1+16] * CN };
        brp  = v2f{ (Bih[r0]   + Bhh[r0])   * CR, (Bih[r1]   + Bhh[r1])   * CR };
        bzp  = v2f{ (Bih[r0+8] + Bhh[r0+8]) * CR, (Bih[r1+8] + Bhh[r1+8]) * CR };
        bnp  = v2f{ Bhh[r0+16] * CN,              Bhh[r1+16] * CN };
        binp = v2f{ Bih[r0+16] * CN,              Bih[r1+16] * CN };
    };

    load_w(eWih, eWhh, eBih, eBhh);

    // ---- one-time convoy-breaking stagger by hardware wave slot ----
    // HW_REG_HW_ID(=4), WAVE_ID field offset 0 width 4 -> imm = 4 | (3<<11)
    {
        const int slot = __builtin_amdgcn_s_getreg(0x1804) & 3;
        #pragma unroll 1
        for (int i = 0; i < slot; ++i) __builtin_amdgcn_s_sleep(2);   // 128 cy each
    }

    const v2f C_NEG2 = {-2.f, -2.f};
    const v2f C_ONE  = { 1.f,  1.f};
    const v2f C_M1   = {-1.f, -1.f};

    v2f hp[4];                                      // hp[m] = {h_{2(u^m)}, h_{2(u^m)+1}}
    #pragma unroll
    for (int m = 0; m < 4; ++m) hp[m] = v2f{0.f, 0.f};

    auto cell = [&](float xs) {
        const v2f xv = { xs, xs };
        // gate matmuls: 24 pk_fma, h consumed via op_sel broadcast
        v2f ar = pk_fma_L0(wr[0], hp[0], brp);
        v2f az = pk_fma_L0(wz[0], hp[0], bzp);
        v2f an = pk_fma_L0(wn[0], hp[0], bnp);
        pk_fma_H(ar, wr[1], hp[0]);
        pk_fma_H(az, wz[1], hp[0]);
        pk_fma_H(an, wn[1], hp[0]);
        #pragma unroll
        for (int m = 1; m < 4; ++m) {
            pk_fma_L(ar, wr[2*m],   hp[m]);
            pk_fma_L(az, wz[2*m],   hp[m]);
            pk_fma_L(an, wn[2*m],   hp[m]);
            pk_fma_H(ar, wr[2*m+1], hp[m]);
            pk_fma_H(az, wz[2*m+1], hp[m]);
            pk_fma_H(an, wn[2*m+1], hp[m]);
        }
        const v2f sr = pk_fma(xv, wirp, ar);        // scaled pre-act r (rows 2u,2u+1)
        const v2f sz = pk_fma(xv, wizp, az);        // scaled pre-act z

        // 4 sigmoids, ONE rcp (merge across r/z and the row pair)
        const float er0 = exp2_fast(sr.x), er1 = exp2_fast(sr.y);
        const float ez0 = exp2_fast(sz.x), ez1 = exp2_fast(sz.y);
        const float dr0 = 1.0f + er0, dr1 = 1.0f + er1;
        const float dz0 = 1.0f + ez0, dz1 = 1.0f + ez1;
        const float P0  = dr0 * dz0,  P1  = dr1 * dz1;
        const float rp  = rcp_fast(P0 * P1);
        const float rpA = rp * P1,    rpB = rp * P0;    // 1/P0, 1/P1
        const v2f r01 = { dz0 * rpA, dz1 * rpB };
        const v2f z01 = { dr0 * rpA, dr1 * rpB };

        // n = tanh-form with shared rcp across the pair
        v2f pre = pk_fma(xv, winp, binp);
        pre = pk_fma(r01, an, pre);
        const float en0 = exp2_fast(pre.x), en1 = exp2_fast(pre.y);
        const float Dn0 = 1.0f + en0, Dn1 = 1.0f + en1;
        const float rpn = rcp_fast(Dn0 * Dn1);
        const v2f rn  = { rpn * Dn1, rpn * Dn0 };
        const v2f n01 = pk_fma(C_NEG2, rn, C_ONE);  // tanh

        const v2f hm = pk_fma(n01, C_M1, hp[0]);    // h - n
        hp[0] = pk_fma(z01, hm, n01);               // h' = n + z*(h-n)

        // allgather: 6 DPP movs (intra-quad)
        const float g0 = hp[0].x, g1 = hp[0].y;
        hp[1] = v2f{ dppf<QP_XOR1>(g0), dppf<QP_XOR1>(g1) };
        hp[2] = v2f{ dppf<QP_XOR2>(g0), dppf<QP_XOR2>(g1) };
        hp[3] = v2f{ dppf<QP_XOR3>(g0), dppf<QP_XOR3>(g1) };
    };

    // ---------------- encoder: 512 steps, prefetch distance 2, tail peeled ----------------
    const float* xp = x + e0;
    float x0 = xp[0];
    float x1 = xp[BATCH];
    xp += 2 * (size_t)BATCH;
    #pragma unroll 2
    for (int t = 0; t < T_IN - 2; ++t) {
        const float x2 = *xp; xp += BATCH;
        cell(x0);
        x0 = x1; x1 = x2;
    }
    cell(x0);      // t = 510
    cell(x1);      // t = 511; x1 == x[511] == decoder first input

    // ---------------- decoder: 128 steps ----------------
    load_w(dWih, dWhh, dBih, dBhh);
    const v2f fwp = v2f{ fcW[r0], fcW[r1] };
    const float fb = fcB[0];

    float inp = x1;
    float* outp = out + e0;
    #pragma unroll 1
    for (int t = 0; t < T_OUT; ++t) {
        cell(inp);
        // y = fc(h'): pair-product then quad butterfly reduce
        const v2f ay = pk_mul(fwp, hp[0]);
        float s = ay.x + ay.y;
        s += dppf<QP_XOR1>(s);
        s += dppf<QP_XOR2>(s);
        const float y = s + fb;
        if (u == 0) outp[t * BATCH] = y;
        inp = y;
    }
}

extern "C" void kernel_launch(void* const* d_in, const int* in_sizes, int n_in,
                              void* d_out, int out_size, void* d_ws, size_t ws_size,
                              hipStream_t stream) {
    const float* x    = (const float*)d_in[0];
    const float* eWih = (const float*)d_in[1];
    const float* eWhh = (const float*)d_in[2];
    const float* eBih = (const float*)d_in[3];
    const float* eBhh = (const float*)d_in[4];
    const float* dWih = (const float*)d_in[5];
    const float* dWhh = (const float*)d_in[6];
    const float* dBih = (const float*)d_in[7];
    const float* dBhh = (const float*)d_in[8];
    const float* fcW  = (const float*)d_in[9];
    const float* fcB  = (const float*)d_in[10];
    float* out = (float*)d_out;

    dim3 grid(BATCH / 64);   // 1024 blocks; 4 lanes/elem, 64 elems/block
    dim3 block(256);
    gru_seq2seq<<<grid, block, 0, stream>>>(x, eWih, eWhh, eBih, eBhh,
                                            dWih, dWhh, dBih, dBhh,
                                            fcW, fcB, out);
}